// Round 13
// baseline (466.413 us; speedup 1.0000x reference)
//
#include <hip/hip_runtime.h>

#define BB 8
#define NN 2048
#define LL 1280
#define HH 160
#define BN (BB*NN)          // 16384
#define NO (2*HH + LL)      // 1600
#define SHIFT 40.0f

typedef __attribute__((ext_vector_type(8))) short short8;
typedef __attribute__((ext_vector_type(4))) float floatx4;
typedef __attribute__((ext_vector_type(16))) float floatx16;

__device__ __forceinline__ unsigned short f2bf(float f) {
    unsigned int u = __builtin_bit_cast(unsigned int, f);
    u = (u + 0x7FFFu + ((u >> 16) & 1u)) >> 16;
    return (unsigned short)u;
}
__device__ __forceinline__ float bf2f(unsigned short h) {
    unsigned int u = ((unsigned int)h) << 16;
    return __builtin_bit_cast(float, u);
}
__device__ __forceinline__ void split2(float f, unsigned short& hi, unsigned short& lo) {
    hi = f2bf(f);
    lo = f2bf(f - bf2f(hi));
}

// Fragment-major layouts:
// 16-row family (lane = ((k>>3)&3)*16 + (row&15)) — q/k, xh/xl, wv, wqk:
//   q/k:  F(m,h)   = (m>>4)*2560  + (h>>5)*512 + ((h>>3)&3)*128 + (m&15)*8 + (h&7)
//   xh/xl:F(m,k)   = (m>>4)*20480 + (k>>5)*512 + ((k>>3)&3)*128 + (m&15)*8 + (k&7)
//   wv:   F(f,k)   = (f>>4)*20480 + (k>>5)*512 + ((k>>3)&3)*128 + (f&15)*8 + (k&7)
//   wqk:  F(o,k)   = (o>>4)*20480 + (k>>5)*512 + ((k>>3)&3)*128 + (o&15)*8 + (k&7)
// 32-row family for the 32x32x16 MFMA (lane = ((k>>3)&1)*32 + (row&31)) — P, vt:
//   P:  F32(r,t) = (r>>5)*65536 + (t>>4)*512 + (((t>>3)&1)*32 + (r&31))*8 + (t&7)
//   vt: F32(f,t) = (f>>5)*65536 + (t>>4)*512 + (((t>>3)&1)*32 + (f&31))*8 + (t&7)
// A 32-row x 16-k chunk = 512 shorts = one contiguous 1KB wave-load.

__device__ __forceinline__ void gl16(const unsigned short* g, unsigned short* l) {
    __builtin_amdgcn_global_load_lds(
        (const __attribute__((address_space(1))) unsigned int*)g,
        (__attribute__((address_space(3))) unsigned int*)l, 16, 0, 0);
}

// ---------------- cast weights (wqk + wv frag-major) ----------------
__global__ __launch_bounds__(256) void cast_w(
    const float* __restrict__ Wq, const float* __restrict__ Wk, const float* __restrict__ Wv,
    unsigned short* __restrict__ wqk_h, unsigned short* __restrict__ wqk_l,
    unsigned short* __restrict__ wv)
{
    int o = blockIdx.x;   // 0..1599
    if (o < 2*HH) {
        const float* src = (o < HH) ? (Wq + (size_t)o * LL) : (Wk + (size_t)(o - HH) * LL);
        unsigned short* dh = wqk_h + (size_t)(o >> 4) * 20480 + (o & 15) * 8;
        unsigned short* dl = wqk_l + (size_t)(o >> 4) * 20480 + (o & 15) * 8;
        for (int c = threadIdx.x; c < LL; c += 256) {
            unsigned short h, l;
            split2(src[c], h, l);
            unsigned off = (unsigned)(c >> 5) * 512 + ((c >> 3) & 3) * 128 + (c & 7);
            dh[off] = h; dl[off] = l;
        }
    } else {
        // wv frag-major (16-row family: consumed by proj_v's 16x16 machine)
        int f = o - 2*HH;
        const float* src = Wv + (size_t)f * LL;
        unsigned short* dstF = wv + (size_t)(f >> 4) * 20480 + (f & 15) * 8;
        for (int c = threadIdx.x * 4; c < LL; c += 256 * 4) {
            float4 v = *(const float4*)(src + c);
            ushort4 u;
            u.x = f2bf(v.x); u.y = f2bf(v.y); u.z = f2bf(v.z); u.w = f2bf(v.w);
            *(ushort4*)(dstF + (size_t)(c >> 5) * 512 + ((c >> 3) & 3) * 128 + (c & 7)) = u;
        }
    }
}

// ---------------- cast x -> bf16x2 (hi+lo) frag-major ----------------
__global__ __launch_bounds__(256) void cast_x(
    const float* __restrict__ x,
    unsigned short* __restrict__ xh, unsigned short* __restrict__ xl)
{
    const int g   = blockIdx.x;              // m16 group 0..1023
    const int tid = threadIdx.x;
    const float* src = x + (size_t)(g * 16 + (tid & 15)) * LL + ((tid >> 4) & 3) * 8;
    unsigned short* dsth = xh + (size_t)g * 20480 + tid * 8;
    unsigned short* dstl = xl + (size_t)g * 20480 + tid * 8;
    const int ks0 = tid >> 6;                // 0..3
    #pragma unroll
    for (int it = 0; it < 10; it++) {
        int k0 = (it * 4 + ks0) * 32;
        float4 f0 = *(const float4*)(src + k0);
        float4 f1 = *(const float4*)(src + k0 + 4);
        float fv[8] = {f0.x, f0.y, f0.z, f0.w, f1.x, f1.y, f1.z, f1.w};
        short8 h8, l8;
        #pragma unroll
        for (int i = 0; i < 8; i++) {
            unsigned short hh, lll;
            split2(fv[i], hh, lll);
            h8[i] = (short)hh; l8[i] = (short)lll;
        }
        *(short8*)(dsth + it * 2048) = h8;
        *(short8*)(dstl + it * 2048) = l8;
    }
}

// ---------------- Kernel 1a v3: q,k projection, direct-frag stream ----------------
__global__ __launch_bounds__(256, 2) void proj_qk(
    const unsigned short* __restrict__ xh, const unsigned short* __restrict__ xl,
    const unsigned short* __restrict__ wh, const unsigned short* __restrict__ wl,
    const float* __restrict__ bq, const float* __restrict__ bk,
    unsigned short* __restrict__ qh, unsigned short* __restrict__ ql,
    unsigned short* __restrict__ kh, unsigned short* __restrict__ kl)
{
    const int mg0 = blockIdx.x * 2;       // m16 group base (32 rows)
    const int tid = threadIdx.x;
    const int wave = tid >> 6, lane = tid & 63;
    const int l15 = lane & 15, l4 = lane >> 4;

    const unsigned aBase = (unsigned)mg0 * 20480u + lane * 8;
    const unsigned bBase = (unsigned)(wave * 5) * 20480u + lane * 8;

    floatx4 acc[2][5] = {};

    #pragma unroll 2
    for (int ks = 0; ks < 40; ks++) {
        const unsigned ko = (unsigned)ks * 512u;
        short8 ah[2], al[2], bh[5], bl[5];
        #pragma unroll
        for (int mf = 0; mf < 2; mf++) {
            ah[mf] = *(const short8*)(xh + aBase + mf * 20480u + ko);
            al[mf] = *(const short8*)(xl + aBase + mf * 20480u + ko);
        }
        #pragma unroll
        for (int nf = 0; nf < 5; nf++) {
            bh[nf] = *(const short8*)(wh + bBase + nf * 20480u + ko);
            bl[nf] = *(const short8*)(wl + bBase + nf * 20480u + ko);
        }
        #pragma unroll
        for (int mf = 0; mf < 2; mf++)
            #pragma unroll
            for (int nf = 0; nf < 5; nf++) {
                acc[mf][nf] = __builtin_amdgcn_mfma_f32_16x16x32_bf16(ah[mf], bh[nf], acc[mf][nf], 0, 0, 0);
                acc[mf][nf] = __builtin_amdgcn_mfma_f32_16x16x32_bf16(al[mf], bh[nf], acc[mf][nf], 0, 0, 0);
                acc[mf][nf] = __builtin_amdgcn_mfma_f32_16x16x32_bf16(ah[mf], bl[nf], acc[mf][nf], 0, 0, 0);
            }
    }

    // epilogue: bias + bf16x2 split + frag-major q/k stores
    #pragma unroll
    for (int nf = 0; nf < 5; nf++) {
        int o = wave * 80 + nf * 16 + l15;
        bool isQ = (o < HH);
        float bias = isQ ? bq[o] : bk[o - HH];
        int oo = isQ ? o : (o - HH);
        unsigned short* dh = isQ ? qh : kh;
        unsigned short* dl = isQ ? ql : kl;
        unsigned ob = (unsigned)(oo >> 5) * 512u + ((oo >> 3) & 3) * 128u + (oo & 7);
        #pragma unroll
        for (int mf = 0; mf < 2; mf++) {
            unsigned fa0 = (unsigned)(mg0 + mf) * 2560u + ob + (l4 * 4) * 8u;
            #pragma unroll
            for (int r = 0; r < 4; r++) {
                float val = acc[mf][nf][r] + bias;
                unsigned short vh, vl;
                split2(val, vh, vl);
                dh[fa0 + r * 8] = vh;
                dl[fa0 + r * 8] = vl;
            }
        }
    }
}

// ---------------- Kernel 1b v3: v projection -> frag32-major vt ----------------
// Same v7 quadrant pipeline; ONLY the epilogue store address function changed
// to the 32-row frag-major layout consumed by pv_gemm's 32x32x16 MFMAs.
__global__ __launch_bounds__(256, 3) void proj_v(
    const unsigned short* __restrict__ xh, const unsigned short* __restrict__ wv,
    const float* __restrict__ bv, unsigned short* __restrict__ vt)
{
    __shared__ __align__(16) unsigned short Sm[3 * 8192];   // 48 KiB

    const int bid = blockIdx.x;         // 0..1279
    const int xcd = bid & 7;
    const int q   = bid >> 3;           // 0..159
    const int mt  = xcd * 16 + q / 10;  // m-tile 0..127 (batch = xcd)
    const int ft  = q % 10;             // f-tile 0..9
    const int m0 = mt * 128;
    const int f0 = ft * 128;

    const int tid = threadIdx.x;
    const int wave = tid >> 6, lane = tid & 63;
    const int l15 = lane & 15, l4 = lane >> 4;
    const int wm = wave >> 1, wn = wave & 1;

    const unsigned short* AF = xh + (size_t)(m0 >> 4) * 20480;
    const unsigned short* BF = wv + (size_t)(f0 >> 4) * 20480;

    const int sp0 = tid, sp1 = 256 + tid;
    const unsigned sa0 = (unsigned)(sp0 >> 6) * 20480u + (sp0 & 63) * 8;
    const unsigned sa1 = (unsigned)(sp1 >> 6) * 20480u + (sp1 & 63) * 8;

    floatx4 acc[4][4] = {};

    auto STAGE = [&](int slot, int ks) {
        unsigned short* A  = Sm + slot * 8192;
        unsigned short* Bs = A + 4096;
        const unsigned ko = (unsigned)ks * 512u;
        gl16(AF + sa0 + ko, A  + sp0 * 8);
        gl16(BF + sa0 + ko, Bs + sp0 * 8);
        gl16(AF + sa1 + ko, A  + sp1 * 8);
        gl16(BF + sa1 + ko, Bs + sp1 * 8);
    };

    auto COMPUTE = [&](int slot) {
        const unsigned short* A  = Sm + slot * 8192;
        const unsigned short* Bs = A + 4096;
        short8 a[4], bb[4];
        #pragma unroll
        for (int mf = 0; mf < 4; mf++)
            a[mf] = *(const short8*)(A + ((wm * 4 + mf) * 64 + lane) * 8);
        #pragma unroll
        for (int nf = 0; nf < 4; nf++)
            bb[nf] = *(const short8*)(Bs + ((wn * 4 + nf) * 64 + lane) * 8);
        __builtin_amdgcn_s_setprio(1);
        #pragma unroll
        for (int mf = 0; mf < 4; mf++)
            #pragma unroll
            for (int nf = 0; nf < 4; nf++)
                acc[mf][nf] = __builtin_amdgcn_mfma_f32_16x16x32_bf16(a[mf], bb[nf], acc[mf][nf], 0, 0, 0);
        __builtin_amdgcn_s_setprio(0);
    };

    STAGE(0, 0); STAGE(1, 1); STAGE(2, 2);

    int s = 0;
    for (int kt = 0; kt < 37; ++kt) {              // 40 K-steps total
        asm volatile("s_waitcnt vmcnt(8)" ::: "memory");
        asm volatile("s_barrier" ::: "memory");
        COMPUTE(s);
        asm volatile("s_barrier" ::: "memory");
        STAGE(s, kt + 3);
        s = (s == 2) ? 0 : s + 1;
    }
    asm volatile("s_waitcnt vmcnt(8)" ::: "memory");
    asm volatile("s_barrier" ::: "memory");
    COMPUTE(s); s = (s == 2) ? 0 : s + 1;
    asm volatile("s_waitcnt vmcnt(4)" ::: "memory");
    asm volatile("s_barrier" ::: "memory");
    COMPUTE(s); s = (s == 2) ? 0 : s + 1;
    asm volatile("s_waitcnt vmcnt(0)" ::: "memory");
    asm volatile("s_barrier" ::: "memory");
    COMPUTE(s);

    // epilogue: bias + frag32-major vt stores (ushort4 over r)
    // t = tokb + mf*16 + l4*4 + r: t>>4 = (tokb>>4)+mf; (t>>3)&1 = l4>>1;
    // t&7 = (l4&1)*4 + r.  f = f0 + wn*64 + nf*16 + l15.
    const int b    = m0 >> 11;                    // == xcd
    const int tokb = (m0 & 2047) + wm * 64;
    unsigned short* vtB = vt + (size_t)b * LL * NN;
    float bvv[4];
    #pragma unroll
    for (int nf = 0; nf < 4; nf++)
        bvv[nf] = bv[f0 + wn * 64 + nf * 16 + l15];

    #pragma unroll
    for (int mf = 0; mf < 4; mf++)
        #pragma unroll
        for (int nf = 0; nf < 4; nf++) {
            int fgrp = (f0 >> 5) + wn * 2 + (nf >> 1);
            int fin  = (nf & 1) * 16 + l15;
            size_t addr = (size_t)fgrp * 65536 + (size_t)((tokb >> 4) + mf) * 512
                        + ((l4 >> 1) * 32 + fin) * 8 + (l4 & 1) * 4;
            ushort4 u;
            u.x = f2bf(acc[mf][nf][0] + bvv[nf]);
            u.y = f2bf(acc[mf][nf][1] + bvv[nf]);
            u.z = f2bf(acc[mf][nf][2] + bvv[nf]);
            u.w = f2bf(acc[mf][nf][3] + bvv[nf]);
            *(ushort4*)(vtB + addr) = u;
        }
}

// ---------------- Kernel 2a v3: S = exp(QK^T - SHIFT) -> frag32-major P ----------------
// Same 64-row L2-reuse structure; ONLY the P-store address function changed
// to the 32-row frag-major layout for pv_gemm's 32x32x16 A-operand.
__global__ __launch_bounds__(512, 2) void s_exp(
    const unsigned short* __restrict__ qhp, const unsigned short* __restrict__ qlp,
    const unsigned short* __restrict__ khp, const unsigned short* __restrict__ klp,
    unsigned short* __restrict__ P, float* __restrict__ Lsum)
{
    __shared__ float sums[8][64];
    const int bid = blockIdx.x;        // 0..255
    const int b   = bid & 7;           // one batch per XCD
    const int i0  = (bid >> 3) * 64;   // 64 q-rows
    const int tid = threadIdx.x;
    const int wave = tid >> 6, lane = tid & 63;
    const int l15 = lane & 15, l4 = lane >> 4;

    // resident A-frags: 4 rowtiles x 5 ks, hi+lo (160 VGPR)
    short8 aqh[4][5], aql[4][5];
    #pragma unroll
    for (int rt = 0; rt < 4; rt++) {
        const size_t rowb = (size_t)((b * NN + i0 + rt * 16) >> 4) * 2560 + lane * 8;
        #pragma unroll
        for (int ks = 0; ks < 5; ks++) {
            aqh[rt][ks] = *(const short8*)&qhp[rowb + ks * 512];
            aql[rt][ks] = *(const short8*)&qlp[rowb + ks * 512];
        }
    }

    float sr[4][4] = {};
    unsigned short* Pb = P + (size_t)b * NN * NN + (size_t)(i0 >> 5) * 65536;

    for (int c0 = 0; c0 < NN; c0 += 512) {
        const int jb = c0 + wave * 64;      // wave's 64-col stripe
        #pragma unroll
        for (int ct = 0; ct < 4; ct++) {
            const int tok0 = jb + ct * 16;                 // multiple of 16
            const size_t kbase = (size_t)((b * NN + tok0) >> 4) * 2560 + lane * 8;
            floatx4 a[4] = {{0,0,0,0},{0,0,0,0},{0,0,0,0},{0,0,0,0}};
            #pragma unroll
            for (int ks = 0; ks < 5; ks++) {
                short8 bh = *(const short8*)&khp[kbase + ks * 512];
                short8 bl = *(const short8*)&klp[kbase + ks * 512];
                #pragma unroll
                for (int rt = 0; rt < 4; rt++) {
                    a[rt] = __builtin_amdgcn_mfma_f32_16x16x32_bf16(aqh[rt][ks], bh, a[rt], 0, 0, 0);
                    a[rt] = __builtin_amdgcn_mfma_f32_16x16x32_bf16(aql[rt][ks], bh, a[rt], 0, 0, 0);
                    a[rt] = __builtin_amdgcn_mfma_f32_16x16x32_bf16(aqh[rt][ks], bl, a[rt], 0, 0, 0);
                }
            }
            // frag32-major P address: t = tok0 + l15 (tok0 mult of 16):
            //   t>>4 = tok0>>4; (t>>3)&1 = l15>>3; t&7 = l15&7.
            // block-local row = rt*16 + l4*4 + r: group = rt>>1,
            //   row&31 = (rt&1)*16 + l4*4 + r.
            const size_t tb32 = (size_t)(tok0 >> 4) * 512 + (l15 >> 3) * 256 + (l15 & 7);
            #pragma unroll
            for (int rt = 0; rt < 4; rt++)
                #pragma unroll
                for (int r = 0; r < 4; r++) {
                    float p = __expf(a[rt][r] - SHIFT);
                    Pb[tb32 + (size_t)(rt >> 1) * 65536
                       + ((rt & 1) * 16 + l4 * 4 + r) * 8] = f2bf(p);
                    sr[rt][r] += p;
                }
        }
    }

    // reduce row sums over l15 (16 lanes), then across the 8 waves via LDS
    #pragma unroll
    for (int rt = 0; rt < 4; rt++)
        #pragma unroll
        for (int r = 0; r < 4; r++) {
            float v = sr[rt][r];
            v += __shfl_xor(v, 1);
            v += __shfl_xor(v, 2);
            v += __shfl_xor(v, 4);
            v += __shfl_xor(v, 8);
            if (l15 == 0) sums[wave][rt * 16 + l4 * 4 + r] = v;
        }
    __syncthreads();
    if (tid < 64) {
        float s = 0.f;
        #pragma unroll
        for (int w = 0; w < 8; w++) s += sums[w][tid];
        Lsum[(size_t)b * NN + i0 + tid] = s;
    }
}

// ---------------- Kernel 2b v9: 32x32x16 frag32-major quadrant GEMM ----------------
// v7 structure (128x128 tile, 4 waves 2x2 quadrants, depth-3, vmcnt(8),
// 48 KB LDS, setprio, XCD swizzle) with the MFMA shape switched to
// v_mfma_f32_32x32x16_bf16: 17% fewer matrix-pipe cycles per K-step
// (1015 vs 845 FLOP/cyc/SIMD at the measured ceilings) and half the
// MFMA/ds_read instruction count. Wave tile 64x64 = 2x2 of 32x32
// (acc 4 x floatx16 = 64 VGPR, same as v7). Staging volumes/counts
// identical -> vmcnt machinery unchanged.
__global__ __launch_bounds__(256, 3) void pv_gemm(
    const unsigned short* __restrict__ P, const unsigned short* __restrict__ vt,
    const float* __restrict__ Lsum,
    const float* __restrict__ x, float* __restrict__ out)
{
    __shared__ __align__(16) unsigned short Sm[3 * 8192];   // 48 KiB

    const int p0 = blockIdx.x;          // 0..1279
    const int b  = p0 & 7;              // one batch per XCD
    const int t  = p0 >> 3;             // 0..159
    const int n0 = (t % 10) * 128;
    const int m0 = (t / 10) * 128;

    const int tid = threadIdx.x;
    const int wave = tid >> 6, lane = tid & 63;
    const int l31 = lane & 31, l5 = lane >> 5;
    const int wm = wave >> 1, wn = wave & 1;

    const unsigned short* PbF = P  + (size_t)b * NN * NN + (size_t)(m0 >> 5) * 65536;
    const unsigned short* VbF = vt + (size_t)b * LL * NN + (size_t)(n0 >> 5) * 65536;

    // staging: granule p (0..511 per matrix): row-group p>>7, inner (p&127)*8
    const int sp0 = tid, sp1 = 256 + tid;
    const unsigned sa0 = (unsigned)(sp0 >> 7) * 65536u + (sp0 & 127) * 8;
    const unsigned sa1 = (unsigned)(sp1 >> 7) * 65536u + (sp1 & 127) * 8;

    floatx16 acc[2][2] = {};

    auto STAGE = [&](int slot, int ks) {
        unsigned short* A  = Sm + slot * 8192;
        unsigned short* Bs = A + 4096;
        const unsigned ko = (unsigned)ks * 1024u;   // K-32 tile = 2 chunks/group
        gl16(PbF + sa0 + ko, A  + sp0 * 8);
        gl16(VbF + sa0 + ko, Bs + sp0 * 8);
        gl16(PbF + sa1 + ko, A  + sp1 * 8);
        gl16(VbF + sa1 + ko, Bs + sp1 * 8);
    };

    auto COMPUTE = [&](int slot) {
        const unsigned short* A  = Sm + slot * 8192;
        const unsigned short* Bs = A + 4096;
        // LDS slot layout: 4 row-groups x {2 k-half chunks of 512 shorts}
        short8 a[2][2], bb[2][2];
        #pragma unroll
        for (int i = 0; i < 2; i++)
            #pragma unroll
            for (int h = 0; h < 2; h++) {
                a[i][h]  = *(const short8*)(A  + ((2 * wm + i) * 2 + h) * 512 + lane * 8);
                bb[i][h] = *(const short8*)(Bs + ((2 * wn + i) * 2 + h) * 512 + lane * 8);
            }
        __builtin_amdgcn_s_setprio(1);
        #pragma unroll
        for (int i = 0; i < 2; i++)
            #pragma unroll
            for (int j = 0; j < 2; j++) {
                acc[i][j] = __builtin_amdgcn_mfma_f32_32x32x16_bf16(a[i][0], bb[j][0], acc[i][j], 0, 0, 0);
                acc[i][j] = __builtin_amdgcn_mfma_f32_32x32x16_bf16(a[i][1], bb[j][1], acc[i][j], 0, 0, 0);
            }
        __builtin_amdgcn_s_setprio(0);
    };

    STAGE(0, 0); STAGE(1, 1); STAGE(2, 2);

    int s = 0;
    for (int kt = 0; kt < 61; ++kt) {
        asm volatile("s_waitcnt vmcnt(8)" ::: "memory");
        asm volatile("s_barrier" ::: "memory");
        COMPUTE(s);
        asm volatile("s_barrier" ::: "memory");
        STAGE(s, kt + 3);
        s = (s == 2) ? 0 : s + 1;
    }
    asm volatile("s_waitcnt vmcnt(8)" ::: "memory");
    asm volatile("s_barrier" ::: "memory");
    COMPUTE(s); s = (s == 2) ? 0 : s + 1;
    asm volatile("s_waitcnt vmcnt(4)" ::: "memory");
    asm volatile("s_barrier" ::: "memory");
    COMPUTE(s); s = (s == 2) ? 0 : s + 1;
    asm volatile("s_waitcnt vmcnt(0)" ::: "memory");
    asm volatile("s_barrier" ::: "memory");
    COMPUTE(s);

    // epilogue: C/D 32x32 layout: col = lane&31, row = (reg&3)+8*(reg>>2)+4*(lane>>5)
    float linv[2][16];
    #pragma unroll
    for (int i = 0; i < 2; i++)
        #pragma unroll
        for (int reg = 0; reg < 16; reg++) {
            int row = m0 + wm * 64 + i * 32 + (reg & 3) + 8 * (reg >> 2) + 4 * l5;
            linv[i][reg] = 1.0f / Lsum[(size_t)b * NN + row];
        }

    #pragma unroll
    for (int i = 0; i < 2; i++)
        #pragma unroll
        for (int j = 0; j < 2; j++)
            #pragma unroll
            for (int reg = 0; reg < 16; reg++) {
                int row = m0 + wm * 64 + i * 32 + (reg & 3) + 8 * (reg >> 2) + 4 * l5;
                int col = n0 + wn * 64 + j * 32 + l31;
                size_t idx = ((size_t)b * NN + row) * LL + col;
                out[idx] = acc[i][j][reg] * linv[i][reg] + x[idx];
            }
}

extern "C" void kernel_launch(void* const* d_in, const int* in_sizes, int n_in,
                              void* d_out, int out_size, void* d_ws, size_t ws_size,
                              hipStream_t stream) {
    const float* x  = (const float*)d_in[0];
    const float* Wq = (const float*)d_in[1];
    const float* bq = (const float*)d_in[2];
    const float* Wk = (const float*)d_in[3];
    const float* bk = (const float*)d_in[4];
    const float* Wv = (const float*)d_in[5];
    const float* bv = (const float*)d_in[6];
    float* out = (float*)d_out;

    // ws layout (~135 MB)
    unsigned short* wqk_h = (unsigned short*)d_ws;            // [20 o16][20480] frag-major
    unsigned short* wqk_l = wqk_h + (size_t)2*HH * LL;
    unsigned short* wv    = wqk_l + (size_t)2*HH * LL;        // [LL*LL] frag-major
    unsigned short* qh    = wv    + (size_t)LL * LL;          // [BN][HH] frag-major
    unsigned short* ql    = qh    + (size_t)BN * HH;
    unsigned short* kh    = ql    + (size_t)BN * HH;
    unsigned short* kl    = kh    + (size_t)BN * HH;
    unsigned short* vt    = kl    + (size_t)BN * HH;          // [BB][LL*NN] frag32-major
    unsigned short* P     = vt    + (size_t)BB * LL * NN;     // [BB][NN*NN] frag32-major
    float*          Lsum  = (float*)(P + (size_t)BB * NN * NN); // [BN]
    // Aliases (sequential-stream ordering makes these safe):
    //   xh (42 MB) aliases P (67 MB): consumed by proj_qk + proj_v, both
    //     complete before s_exp writes P.
    //   xl (42 MB) aliases vt (42 MB, exact fit): consumed only by proj_qk,
    //     which completes before proj_v writes vt.
    unsigned short* xh    = P;
    unsigned short* xl    = vt;

    cast_w<<<dim3(NO), dim3(256), 0, stream>>>(Wq, Wk, Wv, wqk_h, wqk_l, wv);

    cast_x<<<dim3(BN / 16), dim3(256), 0, stream>>>(x, xh, xl);

    // 512 blocks (2/CU), 4 waves: block = 32 rows x all 320 outputs
    proj_qk<<<dim3(BN / 32), dim3(256), 0, stream>>>(
        xh, xl, wqk_h, wqk_l, bq, bk, qh, ql, kh, kl);

    // flat 1280 blocks: xcd = bid&7 owns batch xcd; f-fastest within XCD
    proj_v<<<dim3(1280), dim3(256), 0, stream>>>(xh, wv, bv, vt);

    // flat 256 blocks of 512 threads: b = bid&7 (batch per XCD), 64 rows each
    s_exp<<<dim3(256), dim3(512), 0, stream>>>(qh, ql, kh, kl, P, Lsum);

    // flat 1280 blocks: b = bid&7 (batch per XCD), t = bid>>3 -> (n,m) tile
    pv_gemm<<<dim3(1280), dim3(256), 0, stream>>>(P, vt, Lsum, x, out);
}

// Round 14
// 432.828 us; speedup vs baseline: 1.0776x; 1.0776x over previous
//
#include <hip/hip_runtime.h>

#define BB 8
#define NN 2048
#define LL 1280
#define HH 160
#define BN (BB*NN)          // 16384
#define NO (2*HH + LL)      // 1600
#define SHIFT 40.0f

typedef __attribute__((ext_vector_type(8))) short short8;
typedef __attribute__((ext_vector_type(4))) float floatx4;

__device__ __forceinline__ unsigned short f2bf(float f) {
    unsigned int u = __builtin_bit_cast(unsigned int, f);
    u = (u + 0x7FFFu + ((u >> 16) & 1u)) >> 16;
    return (unsigned short)u;
}
__device__ __forceinline__ float bf2f(unsigned short h) {
    unsigned int u = ((unsigned int)h) << 16;
    return __builtin_bit_cast(float, u);
}
__device__ __forceinline__ void split2(float f, unsigned short& hi, unsigned short& lo) {
    hi = f2bf(f);
    lo = f2bf(f - bf2f(hi));
}

// Fragment-major layouts (MFMA-native, lane = ((k>>3)&3)*16 + (row&15)):
//   q/k:  F(m,h)   = (m>>4)*2560  + (h>>5)*512 + ((h>>3)&3)*128 + (m&15)*8 + (h&7)
//   P:    F(r,tok) = (r>>4)*32768 + (tok>>5)*512 + ((tok>>3)&3)*128 + (r&15)*8 + (tok&7)
//   vt:   F(f,tok) = (f>>4)*32768 + (tok>>5)*512 + ((tok>>3)&3)*128 + (f&15)*8 + (tok&7)
//   xh/xl:F(m,k)   = (m>>4)*20480 + (k>>5)*512 + ((k>>3)&3)*128 + (m&15)*8 + (k&7)
//   wv:   F(f,k)   = (f>>4)*20480 + (k>>5)*512 + ((k>>3)&3)*128 + (f&15)*8 + (k&7)
//   wqk:  F(o,k)   = (o>>4)*20480 + (k>>5)*512 + ((k>>3)&3)*128 + (o&15)*8 + (k&7)
// A 16-row x 32-k fragment = one contiguous 1KB wave-load / gload_lds chunk.

__device__ __forceinline__ void gl16(const unsigned short* g, unsigned short* l) {
    __builtin_amdgcn_global_load_lds(
        (const __attribute__((address_space(1))) unsigned int*)g,
        (__attribute__((address_space(3))) unsigned int*)l, 16, 0, 0);
}

// ---------------- cast weights (wqk + wv frag-major) ----------------
__global__ __launch_bounds__(256) void cast_w(
    const float* __restrict__ Wq, const float* __restrict__ Wk, const float* __restrict__ Wv,
    unsigned short* __restrict__ wqk_h, unsigned short* __restrict__ wqk_l,
    unsigned short* __restrict__ wv)
{
    int o = blockIdx.x;   // 0..1599
    if (o < 2*HH) {
        const float* src = (o < HH) ? (Wq + (size_t)o * LL) : (Wk + (size_t)(o - HH) * LL);
        unsigned short* dh = wqk_h + (size_t)(o >> 4) * 20480 + (o & 15) * 8;
        unsigned short* dl = wqk_l + (size_t)(o >> 4) * 20480 + (o & 15) * 8;
        for (int c = threadIdx.x; c < LL; c += 256) {
            unsigned short h, l;
            split2(src[c], h, l);
            unsigned off = (unsigned)(c >> 5) * 512 + ((c >> 3) & 3) * 128 + (c & 7);
            dh[off] = h; dl[off] = l;
        }
    } else {
        // wv frag-major
        int f = o - 2*HH;
        const float* src = Wv + (size_t)f * LL;
        unsigned short* dstF = wv + (size_t)(f >> 4) * 20480 + (f & 15) * 8;
        for (int c = threadIdx.x * 4; c < LL; c += 256 * 4) {
            float4 v = *(const float4*)(src + c);
            ushort4 u;
            u.x = f2bf(v.x); u.y = f2bf(v.y); u.z = f2bf(v.z); u.w = f2bf(v.w);
            *(ushort4*)(dstF + (size_t)(c >> 5) * 512 + ((c >> 3) & 3) * 128 + (c & 7)) = u;
        }
    }
}

// ---------------- cast x -> bf16x2 (hi+lo) frag-major ----------------
__global__ __launch_bounds__(256) void cast_x(
    const float* __restrict__ x,
    unsigned short* __restrict__ xh, unsigned short* __restrict__ xl)
{
    const int g   = blockIdx.x;              // m16 group 0..1023
    const int tid = threadIdx.x;
    const float* src = x + (size_t)(g * 16 + (tid & 15)) * LL + ((tid >> 4) & 3) * 8;
    unsigned short* dsth = xh + (size_t)g * 20480 + tid * 8;
    unsigned short* dstl = xl + (size_t)g * 20480 + tid * 8;
    const int ks0 = tid >> 6;                // 0..3
    #pragma unroll
    for (int it = 0; it < 10; it++) {
        int k0 = (it * 4 + ks0) * 32;
        float4 f0 = *(const float4*)(src + k0);
        float4 f1 = *(const float4*)(src + k0 + 4);
        float fv[8] = {f0.x, f0.y, f0.z, f0.w, f1.x, f1.y, f1.z, f1.w};
        short8 h8, l8;
        #pragma unroll
        for (int i = 0; i < 8; i++) {
            unsigned short hh, lll;
            split2(fv[i], hh, lll);
            h8[i] = (short)hh; l8[i] = (short)lll;
        }
        *(short8*)(dsth + it * 2048) = h8;
        *(short8*)(dstl + it * 2048) = l8;
    }
}

// ---------------- Kernel 1a v3: q,k projection, direct-frag stream ----------------
__global__ __launch_bounds__(256, 2) void proj_qk(
    const unsigned short* __restrict__ xh, const unsigned short* __restrict__ xl,
    const unsigned short* __restrict__ wh, const unsigned short* __restrict__ wl,
    const float* __restrict__ bq, const float* __restrict__ bk,
    unsigned short* __restrict__ qh, unsigned short* __restrict__ ql,
    unsigned short* __restrict__ kh, unsigned short* __restrict__ kl)
{
    const int mg0 = blockIdx.x * 2;       // m16 group base (32 rows)
    const int tid = threadIdx.x;
    const int wave = tid >> 6, lane = tid & 63;
    const int l15 = lane & 15, l4 = lane >> 4;

    const unsigned aBase = (unsigned)mg0 * 20480u + lane * 8;
    const unsigned bBase = (unsigned)(wave * 5) * 20480u + lane * 8;

    floatx4 acc[2][5] = {};

    #pragma unroll 2
    for (int ks = 0; ks < 40; ks++) {
        const unsigned ko = (unsigned)ks * 512u;
        short8 ah[2], al[2], bh[5], bl[5];
        #pragma unroll
        for (int mf = 0; mf < 2; mf++) {
            ah[mf] = *(const short8*)(xh + aBase + mf * 20480u + ko);
            al[mf] = *(const short8*)(xl + aBase + mf * 20480u + ko);
        }
        #pragma unroll
        for (int nf = 0; nf < 5; nf++) {
            bh[nf] = *(const short8*)(wh + bBase + nf * 20480u + ko);
            bl[nf] = *(const short8*)(wl + bBase + nf * 20480u + ko);
        }
        #pragma unroll
        for (int mf = 0; mf < 2; mf++)
            #pragma unroll
            for (int nf = 0; nf < 5; nf++) {
                acc[mf][nf] = __builtin_amdgcn_mfma_f32_16x16x32_bf16(ah[mf], bh[nf], acc[mf][nf], 0, 0, 0);
                acc[mf][nf] = __builtin_amdgcn_mfma_f32_16x16x32_bf16(al[mf], bh[nf], acc[mf][nf], 0, 0, 0);
                acc[mf][nf] = __builtin_amdgcn_mfma_f32_16x16x32_bf16(ah[mf], bl[nf], acc[mf][nf], 0, 0, 0);
            }
    }

    // epilogue: bias + bf16x2 split + frag-major q/k stores
    #pragma unroll
    for (int nf = 0; nf < 5; nf++) {
        int o = wave * 80 + nf * 16 + l15;
        bool isQ = (o < HH);
        float bias = isQ ? bq[o] : bk[o - HH];
        int oo = isQ ? o : (o - HH);
        unsigned short* dh = isQ ? qh : kh;
        unsigned short* dl = isQ ? ql : kl;
        unsigned ob = (unsigned)(oo >> 5) * 512u + ((oo >> 3) & 3) * 128u + (oo & 7);
        #pragma unroll
        for (int mf = 0; mf < 2; mf++) {
            unsigned fa0 = (unsigned)(mg0 + mf) * 2560u + ob + (l4 * 4) * 8u;
            #pragma unroll
            for (int r = 0; r < 4; r++) {
                float val = acc[mf][nf][r] + bias;
                unsigned short vh, vl;
                split2(val, vh, vl);
                dh[fa0 + r * 8] = vh;
                dl[fa0 + r * 8] = vl;
            }
        }
    }
}

// ---------------- Kernel 1b v2: v projection, v7 quadrant pipeline ----------------
__global__ __launch_bounds__(256, 3) void proj_v(
    const unsigned short* __restrict__ xh, const unsigned short* __restrict__ wv,
    const float* __restrict__ bv, unsigned short* __restrict__ vt)
{
    __shared__ __align__(16) unsigned short Sm[3 * 8192];   // 48 KiB

    const int bid = blockIdx.x;         // 0..1279
    const int xcd = bid & 7;
    const int q   = bid >> 3;           // 0..159
    const int mt  = xcd * 16 + q / 10;  // m-tile 0..127 (batch = xcd)
    const int ft  = q % 10;             // f-tile 0..9
    const int m0 = mt * 128;
    const int f0 = ft * 128;

    const int tid = threadIdx.x;
    const int wave = tid >> 6, lane = tid & 63;
    const int l15 = lane & 15, l4 = lane >> 4;
    const int wm = wave >> 1, wn = wave & 1;

    const unsigned short* AF = xh + (size_t)(m0 >> 4) * 20480;
    const unsigned short* BF = wv + (size_t)(f0 >> 4) * 20480;

    const int sp0 = tid, sp1 = 256 + tid;
    const unsigned sa0 = (unsigned)(sp0 >> 6) * 20480u + (sp0 & 63) * 8;
    const unsigned sa1 = (unsigned)(sp1 >> 6) * 20480u + (sp1 & 63) * 8;

    floatx4 acc[4][4] = {};

    auto STAGE = [&](int slot, int ks) {
        unsigned short* A  = Sm + slot * 8192;
        unsigned short* Bs = A + 4096;
        const unsigned ko = (unsigned)ks * 512u;
        gl16(AF + sa0 + ko, A  + sp0 * 8);
        gl16(BF + sa0 + ko, Bs + sp0 * 8);
        gl16(AF + sa1 + ko, A  + sp1 * 8);
        gl16(BF + sa1 + ko, Bs + sp1 * 8);
    };

    auto COMPUTE = [&](int slot) {
        const unsigned short* A  = Sm + slot * 8192;
        const unsigned short* Bs = A + 4096;
        short8 a[4], bb[4];
        #pragma unroll
        for (int mf = 0; mf < 4; mf++)
            a[mf] = *(const short8*)(A + ((wm * 4 + mf) * 64 + lane) * 8);
        #pragma unroll
        for (int nf = 0; nf < 4; nf++)
            bb[nf] = *(const short8*)(Bs + ((wn * 4 + nf) * 64 + lane) * 8);
        __builtin_amdgcn_s_setprio(1);
        #pragma unroll
        for (int mf = 0; mf < 4; mf++)
            #pragma unroll
            for (int nf = 0; nf < 4; nf++)
                acc[mf][nf] = __builtin_amdgcn_mfma_f32_16x16x32_bf16(a[mf], bb[nf], acc[mf][nf], 0, 0, 0);
        __builtin_amdgcn_s_setprio(0);
    };

    STAGE(0, 0); STAGE(1, 1); STAGE(2, 2);

    int s = 0;
    for (int kt = 0; kt < 37; ++kt) {              // 40 K-steps total
        asm volatile("s_waitcnt vmcnt(8)" ::: "memory");
        asm volatile("s_barrier" ::: "memory");
        COMPUTE(s);
        asm volatile("s_barrier" ::: "memory");
        STAGE(s, kt + 3);
        s = (s == 2) ? 0 : s + 1;
    }
    asm volatile("s_waitcnt vmcnt(8)" ::: "memory");
    asm volatile("s_barrier" ::: "memory");
    COMPUTE(s); s = (s == 2) ? 0 : s + 1;
    asm volatile("s_waitcnt vmcnt(4)" ::: "memory");
    asm volatile("s_barrier" ::: "memory");
    COMPUTE(s); s = (s == 2) ? 0 : s + 1;
    asm volatile("s_waitcnt vmcnt(0)" ::: "memory");
    asm volatile("s_barrier" ::: "memory");
    COMPUTE(s);

    // epilogue: bias + direct frag-major vt stores (ushort4 over r)
    const int b    = m0 >> 11;                    // == xcd
    const int tokb = (m0 & 2047) + wm * 64;
    unsigned short* vtB = vt + (size_t)b * LL * NN;
    float bvv[4];
    #pragma unroll
    for (int nf = 0; nf < 4; nf++)
        bvv[nf] = bv[f0 + wn * 64 + nf * 16 + l15];

    #pragma unroll
    for (int mf = 0; mf < 4; mf++)
        #pragma unroll
        for (int nf = 0; nf < 4; nf++) {
            int f   = f0 + wn * 64 + nf * 16 + l15;
            int tok = tokb + mf * 16 + l4 * 4;    // +r, r=0..3 contiguous in (tok&7)
            ushort4 u;
            u.x = f2bf(acc[mf][nf][0] + bvv[nf]);
            u.y = f2bf(acc[mf][nf][1] + bvv[nf]);
            u.z = f2bf(acc[mf][nf][2] + bvv[nf]);
            u.w = f2bf(acc[mf][nf][3] + bvv[nf]);
            *(ushort4*)(vtB + (size_t)(f >> 4) * 32768 + (tok >> 5) * 512
                        + ((tok >> 3) & 3) * 128 + (f & 15) * 8 + (tok & 7)) = u;
        }
}

// ---------------- Kernel 2a v2: S = exp(QK^T - SHIFT), 64-row blocks ----------------
__global__ __launch_bounds__(512, 2) void s_exp(
    const unsigned short* __restrict__ qhp, const unsigned short* __restrict__ qlp,
    const unsigned short* __restrict__ khp, const unsigned short* __restrict__ klp,
    unsigned short* __restrict__ P, float* __restrict__ Lsum)
{
    __shared__ float sums[8][64];
    const int bid = blockIdx.x;        // 0..255
    const int b   = bid & 7;           // one batch per XCD
    const int i0  = (bid >> 3) * 64;   // 64 q-rows
    const int tid = threadIdx.x;
    const int wave = tid >> 6, lane = tid & 63;
    const int l15 = lane & 15, l4 = lane >> 4;

    // resident A-frags: 4 rowtiles x 5 ks, hi+lo (160 VGPR)
    short8 aqh[4][5], aql[4][5];
    #pragma unroll
    for (int rt = 0; rt < 4; rt++) {
        const size_t rowb = (size_t)((b * NN + i0 + rt * 16) >> 4) * 2560 + lane * 8;
        #pragma unroll
        for (int ks = 0; ks < 5; ks++) {
            aqh[rt][ks] = *(const short8*)&qhp[rowb + ks * 512];
            aql[rt][ks] = *(const short8*)&qlp[rowb + ks * 512];
        }
    }

    float sr[4][4] = {};
    unsigned short* Pb = P + (size_t)b * NN * NN + (size_t)(i0 >> 4) * 32768;

    for (int c0 = 0; c0 < NN; c0 += 512) {
        const int jb = c0 + wave * 64;      // wave's 64-col stripe
        #pragma unroll
        for (int ct = 0; ct < 4; ct++) {
            const int tok0 = jb + ct * 16;                 // multiple of 16
            const int tok  = tok0 + l15;
            const size_t kbase = (size_t)((b * NN + tok0) >> 4) * 2560 + lane * 8;
            floatx4 a[4] = {{0,0,0,0},{0,0,0,0},{0,0,0,0},{0,0,0,0}};
            #pragma unroll
            for (int ks = 0; ks < 5; ks++) {
                short8 bh = *(const short8*)&khp[kbase + ks * 512];
                short8 bl = *(const short8*)&klp[kbase + ks * 512];
                #pragma unroll
                for (int rt = 0; rt < 4; rt++) {
                    a[rt] = __builtin_amdgcn_mfma_f32_16x16x32_bf16(aqh[rt][ks], bh, a[rt], 0, 0, 0);
                    a[rt] = __builtin_amdgcn_mfma_f32_16x16x32_bf16(aql[rt][ks], bh, a[rt], 0, 0, 0);
                    a[rt] = __builtin_amdgcn_mfma_f32_16x16x32_bf16(aqh[rt][ks], bl, a[rt], 0, 0, 0);
                }
            }
            const size_t tbase = (size_t)(tok >> 5) * 512 + ((tok >> 3) & 3) * 128 + (tok & 7);
            #pragma unroll
            for (int rt = 0; rt < 4; rt++)
                #pragma unroll
                for (int r = 0; r < 4; r++) {
                    float p = __expf(a[rt][r] - SHIFT);
                    Pb[tbase + (size_t)rt * 32768 + (l4 * 4 + r) * 8] = f2bf(p);
                    sr[rt][r] += p;
                }
        }
    }

    // reduce row sums over l15 (16 lanes), then across the 8 waves via LDS
    #pragma unroll
    for (int rt = 0; rt < 4; rt++)
        #pragma unroll
        for (int r = 0; r < 4; r++) {
            float v = sr[rt][r];
            v += __shfl_xor(v, 1);
            v += __shfl_xor(v, 2);
            v += __shfl_xor(v, 4);
            v += __shfl_xor(v, 8);
            if (l15 == 0) sums[wave][rt * 16 + l4 * 4 + r] = v;
        }
    __syncthreads();
    if (tid < 64) {
        float s = 0.f;
        #pragma unroll
        for (int w = 0; w < 8; w++) s += sums[w][tid];
        Lsum[(size_t)b * NN + i0 + tid] = s;
    }
}

// ---------------- Kernel 2b v10: 2-wave 64x128-wave frag-major GEMM ----------------
// v7 (4 waves 2x2, 48 KB traffic/64 MFMA) is LDS-issue-bound (~240 B/cyc
// effective, MFMA idle 60%). v10 keeps EVERYTHING verified (128x128 tile,
// BK=32, depth-3 rotating 48 KB LDS, counted vmcnt, setprio, XCD swizzle,
// frag-major linear staging) and changes ONLY the wave decomposition:
// 2 waves, each 64x128 (acc 4x8): block LDS traffic 40 KB per 64 MFMA
// (-17%) and 2-wave barriers. 128 threads -> 8 gl16/thread/tile ->
// counted waits become vmcnt(16)/(8)/(0). 1280 blocks, 3 blocks/CU (LDS).
__global__ __launch_bounds__(128, 2) void pv_gemm(
    const unsigned short* __restrict__ P, const unsigned short* __restrict__ vt,
    const float* __restrict__ Lsum,
    const float* __restrict__ x, float* __restrict__ out)
{
    __shared__ __align__(16) unsigned short Sm[3 * 8192];   // 48 KiB

    const int p0 = blockIdx.x;          // 0..1279
    const int b  = p0 & 7;              // one batch per XCD
    const int t  = p0 >> 3;             // 0..159
    const int n0 = (t % 10) * 128;
    const int m0 = (t / 10) * 128;

    const int tid = threadIdx.x;
    const int wm  = tid >> 6, lane = tid & 63;   // wave = M-half owner
    const int l15 = lane & 15, l4 = lane >> 4;

    const unsigned short* PbF = P  + (size_t)b * NN * NN + (size_t)(m0 >> 4) * 32768;
    const unsigned short* VbF = vt + (size_t)b * LL * NN + (size_t)(n0 >> 4) * 32768;

    // staging: 512 granules per matrix; thread handles p = i*128+tid, i=0..3
    unsigned sa[4], dof[4];
    #pragma unroll
    for (int i = 0; i < 4; i++) {
        int p = i * 128 + tid;
        sa[i]  = (unsigned)(p >> 6) * 32768u + (p & 63) * 8;
        dof[i] = (unsigned)p * 8;
    }

    floatx4 acc[4][8] = {};

    auto STAGE = [&](int slot, int ks) {
        unsigned short* A  = Sm + slot * 8192;
        unsigned short* Bs = A + 4096;
        const unsigned ko = (unsigned)ks * 512u;
        #pragma unroll
        for (int i = 0; i < 4; i++) {
            gl16(PbF + sa[i] + ko, A  + dof[i]);
            gl16(VbF + sa[i] + ko, Bs + dof[i]);
        }
    };

    auto COMPUTE = [&](int slot) {
        const unsigned short* A  = Sm + slot * 8192;
        const unsigned short* Bs = A + 4096;
        short8 a[4];
        #pragma unroll
        for (int mf = 0; mf < 4; mf++)
            a[mf] = *(const short8*)(A + ((wm * 4 + mf) * 64 + lane) * 8);
        __builtin_amdgcn_s_setprio(1);
        #pragma unroll
        for (int nf = 0; nf < 8; nf++) {
            short8 bb = *(const short8*)(Bs + (nf * 64 + lane) * 8);
            #pragma unroll
            for (int mf = 0; mf < 4; mf++)
                acc[mf][nf] = __builtin_amdgcn_mfma_f32_16x16x32_bf16(a[mf], bb, acc[mf][nf], 0, 0, 0);
        }
        __builtin_amdgcn_s_setprio(0);
    };

    STAGE(0, 0); STAGE(1, 1); STAGE(2, 2);   // 24 loads/thread in flight

    int s = 0;
    for (int kt = 0; kt < 61; ++kt) {
        asm volatile("s_waitcnt vmcnt(16)" ::: "memory");  // tile kt landed (own 8)
        asm volatile("s_barrier" ::: "memory");            // cross-wave visibility
        COMPUTE(s);
        asm volatile("s_barrier" ::: "memory");            // slot free
        STAGE(s, kt + 3);
        s = (s == 2) ? 0 : s + 1;
    }
    asm volatile("s_waitcnt vmcnt(16)" ::: "memory");
    asm volatile("s_barrier" ::: "memory");
    COMPUTE(s); s = (s == 2) ? 0 : s + 1;
    asm volatile("s_waitcnt vmcnt(8)" ::: "memory");
    asm volatile("s_barrier" ::: "memory");
    COMPUTE(s); s = (s == 2) ? 0 : s + 1;
    asm volatile("s_waitcnt vmcnt(0)" ::: "memory");
    asm volatile("s_barrier" ::: "memory");
    COMPUTE(s);

    float linv[4][4];
    #pragma unroll
    for (int mf = 0; mf < 4; mf++)
        #pragma unroll
        for (int r = 0; r < 4; r++)
            linv[mf][r] = 1.0f / Lsum[(size_t)b * NN + m0 + wm * 64 + mf * 16 + l4 * 4 + r];

    #pragma unroll
    for (int mf = 0; mf < 4; mf++)
        #pragma unroll
        for (int nf = 0; nf < 8; nf++)
            #pragma unroll
            for (int r = 0; r < 4; r++) {
                int row = m0 + wm * 64 + mf * 16 + l4 * 4 + r;
                int col = n0 + nf * 16 + l15;
                size_t idx = ((size_t)b * NN + row) * LL + col;
                out[idx] = acc[mf][nf][r] * linv[mf][r] + x[idx];
            }
}

extern "C" void kernel_launch(void* const* d_in, const int* in_sizes, int n_in,
                              void* d_out, int out_size, void* d_ws, size_t ws_size,
                              hipStream_t stream) {
    const float* x  = (const float*)d_in[0];
    const float* Wq = (const float*)d_in[1];
    const float* bq = (const float*)d_in[2];
    const float* Wk = (const float*)d_in[3];
    const float* bk = (const float*)d_in[4];
    const float* Wv = (const float*)d_in[5];
    const float* bv = (const float*)d_in[6];
    float* out = (float*)d_out;

    // ws layout (~135 MB)
    unsigned short* wqk_h = (unsigned short*)d_ws;            // [20 o16][20480] frag-major
    unsigned short* wqk_l = wqk_h + (size_t)2*HH * LL;
    unsigned short* wv    = wqk_l + (size_t)2*HH * LL;        // [LL*LL] frag-major
    unsigned short* qh    = wv    + (size_t)LL * LL;          // [BN][HH] frag-major
    unsigned short* ql    = qh    + (size_t)BN * HH;
    unsigned short* kh    = ql    + (size_t)BN * HH;
    unsigned short* kl    = kh    + (size_t)BN * HH;
    unsigned short* vt    = kl    + (size_t)BN * HH;          // [BB][LL*NN] frag-major
    unsigned short* P     = vt    + (size_t)BB * LL * NN;     // [BB][NN*NN] frag-major
    float*          Lsum  = (float*)(P + (size_t)BB * NN * NN); // [BN]
    // Aliases (sequential-stream ordering makes these safe):
    //   xh (42 MB) aliases P (67 MB): consumed by proj_qk + proj_v, both
    //     complete before s_exp writes P.
    //   xl (42 MB) aliases vt (42 MB, exact fit): consumed only by proj_qk,
    //     which completes before proj_v writes vt.
    unsigned short* xh    = P;
    unsigned short* xl    = vt;

    cast_w<<<dim3(NO), dim3(256), 0, stream>>>(Wq, Wk, Wv, wqk_h, wqk_l, wv);

    cast_x<<<dim3(BN / 16), dim3(256), 0, stream>>>(x, xh, xl);

    // 512 blocks (2/CU), 4 waves: block = 32 rows x all 320 outputs
    proj_qk<<<dim3(BN / 32), dim3(256), 0, stream>>>(
        xh, xl, wqk_h, wqk_l, bq, bk, qh, ql, kh, kl);

    // flat 1280 blocks: xcd = bid&7 owns batch xcd; f-fastest within XCD
    proj_v<<<dim3(1280), dim3(256), 0, stream>>>(xh, wv, bv, vt);

    // flat 256 blocks of 512 threads: b = bid&7 (batch per XCD), 64 rows each
    s_exp<<<dim3(256), dim3(512), 0, stream>>>(qh, ql, kh, kl, P, Lsum);

    // flat 1280 blocks of 128 threads: b = bid&7 (batch per XCD)
    pv_gemm<<<dim3(1280), dim3(128), 0, stream>>>(P, vt, Lsum, x, out);
}

// Round 15
// 414.747 us; speedup vs baseline: 1.1246x; 1.0436x over previous
//
#include <hip/hip_runtime.h>

#define BB 8
#define NN 2048
#define LL 1280
#define HH 160
#define BN (BB*NN)          // 16384
#define NO (2*HH + LL)      // 1600
#define SHIFT 40.0f

typedef __attribute__((ext_vector_type(8))) short short8;
typedef __attribute__((ext_vector_type(4))) float floatx4;

__device__ __forceinline__ unsigned short f2bf(float f) {
    unsigned int u = __builtin_bit_cast(unsigned int, f);
    u = (u + 0x7FFFu + ((u >> 16) & 1u)) >> 16;
    return (unsigned short)u;
}
__device__ __forceinline__ float bf2f(unsigned short h) {
    unsigned int u = ((unsigned int)h) << 16;
    return __builtin_bit_cast(float, u);
}
__device__ __forceinline__ void split2(float f, unsigned short& hi, unsigned short& lo) {
    hi = f2bf(f);
    lo = f2bf(f - bf2f(hi));
}

// Fragment-major layouts (MFMA-native, lane = ((k>>3)&3)*16 + (row&15)):
//   q/k:  F(m,h)   = (m>>4)*2560  + (h>>5)*512 + ((h>>3)&3)*128 + (m&15)*8 + (h&7)
//   P:    F(r,tok) = (r>>4)*32768 + (tok>>5)*512 + ((tok>>3)&3)*128 + (r&15)*8 + (tok&7)
//   vt:   F(f,tok) = (f>>4)*32768 + (tok>>5)*512 + ((tok>>3)&3)*128 + (f&15)*8 + (tok&7)
//   xh/xl:F(m,k)   = (m>>4)*20480 + (k>>5)*512 + ((k>>3)&3)*128 + (m&15)*8 + (k&7)
//   wv:   F(f,k)   = (f>>4)*20480 + (k>>5)*512 + ((k>>3)&3)*128 + (f&15)*8 + (k&7)
//   wqk:  F(o,k)   = (o>>4)*20480 + (k>>5)*512 + ((k>>3)&3)*128 + (o&15)*8 + (k&7)
// A 16-row x 32-k fragment = one contiguous 1KB wave-load / gload_lds chunk.

__device__ __forceinline__ void gl16(const unsigned short* g, unsigned short* l) {
    __builtin_amdgcn_global_load_lds(
        (const __attribute__((address_space(1))) unsigned int*)g,
        (__attribute__((address_space(3))) unsigned int*)l, 16, 0, 0);
}

// ---------------- cast weights (wqk + wv frag-major) ----------------
__global__ __launch_bounds__(256) void cast_w(
    const float* __restrict__ Wq, const float* __restrict__ Wk, const float* __restrict__ Wv,
    unsigned short* __restrict__ wqk_h, unsigned short* __restrict__ wqk_l,
    unsigned short* __restrict__ wv)
{
    int o = blockIdx.x;   // 0..1599
    if (o < 2*HH) {
        const float* src = (o < HH) ? (Wq + (size_t)o * LL) : (Wk + (size_t)(o - HH) * LL);
        unsigned short* dh = wqk_h + (size_t)(o >> 4) * 20480 + (o & 15) * 8;
        unsigned short* dl = wqk_l + (size_t)(o >> 4) * 20480 + (o & 15) * 8;
        for (int c = threadIdx.x; c < LL; c += 256) {
            unsigned short h, l;
            split2(src[c], h, l);
            unsigned off = (unsigned)(c >> 5) * 512 + ((c >> 3) & 3) * 128 + (c & 7);
            dh[off] = h; dl[off] = l;
        }
    } else {
        // wv frag-major
        int f = o - 2*HH;
        const float* src = Wv + (size_t)f * LL;
        unsigned short* dstF = wv + (size_t)(f >> 4) * 20480 + (f & 15) * 8;
        for (int c = threadIdx.x * 4; c < LL; c += 256 * 4) {
            float4 v = *(const float4*)(src + c);
            ushort4 u;
            u.x = f2bf(v.x); u.y = f2bf(v.y); u.z = f2bf(v.z); u.w = f2bf(v.w);
            *(ushort4*)(dstF + (size_t)(c >> 5) * 512 + ((c >> 3) & 3) * 128 + (c & 7)) = u;
        }
    }
}

// ---------------- cast x -> bf16x2 (hi+lo) frag-major ----------------
__global__ __launch_bounds__(256) void cast_x(
    const float* __restrict__ x,
    unsigned short* __restrict__ xh, unsigned short* __restrict__ xl)
{
    const int g   = blockIdx.x;              // m16 group 0..1023
    const int tid = threadIdx.x;
    const float* src = x + (size_t)(g * 16 + (tid & 15)) * LL + ((tid >> 4) & 3) * 8;
    unsigned short* dsth = xh + (size_t)g * 20480 + tid * 8;
    unsigned short* dstl = xl + (size_t)g * 20480 + tid * 8;
    const int ks0 = tid >> 6;                // 0..3
    #pragma unroll
    for (int it = 0; it < 10; it++) {
        int k0 = (it * 4 + ks0) * 32;
        float4 f0 = *(const float4*)(src + k0);
        float4 f1 = *(const float4*)(src + k0 + 4);
        float fv[8] = {f0.x, f0.y, f0.z, f0.w, f1.x, f1.y, f1.z, f1.w};
        short8 h8, l8;
        #pragma unroll
        for (int i = 0; i < 8; i++) {
            unsigned short hh, lll;
            split2(fv[i], hh, lll);
            h8[i] = (short)hh; l8[i] = (short)lll;
        }
        *(short8*)(dsth + it * 2048) = h8;
        *(short8*)(dstl + it * 2048) = l8;
    }
}

// ---------------- Kernel 1a v3: q,k projection, direct-frag stream ----------------
__global__ __launch_bounds__(256, 2) void proj_qk(
    const unsigned short* __restrict__ xh, const unsigned short* __restrict__ xl,
    const unsigned short* __restrict__ wh, const unsigned short* __restrict__ wl,
    const float* __restrict__ bq, const float* __restrict__ bk,
    unsigned short* __restrict__ qh, unsigned short* __restrict__ ql,
    unsigned short* __restrict__ kh, unsigned short* __restrict__ kl)
{
    const int mg0 = blockIdx.x * 2;       // m16 group base (32 rows)
    const int tid = threadIdx.x;
    const int wave = tid >> 6, lane = tid & 63;
    const int l15 = lane & 15, l4 = lane >> 4;

    const unsigned aBase = (unsigned)mg0 * 20480u + lane * 8;
    const unsigned bBase = (unsigned)(wave * 5) * 20480u + lane * 8;

    floatx4 acc[2][5] = {};

    #pragma unroll 2
    for (int ks = 0; ks < 40; ks++) {
        const unsigned ko = (unsigned)ks * 512u;
        short8 ah[2], al[2], bh[5], bl[5];
        #pragma unroll
        for (int mf = 0; mf < 2; mf++) {
            ah[mf] = *(const short8*)(xh + aBase + mf * 20480u + ko);
            al[mf] = *(const short8*)(xl + aBase + mf * 20480u + ko);
        }
        #pragma unroll
        for (int nf = 0; nf < 5; nf++) {
            bh[nf] = *(const short8*)(wh + bBase + nf * 20480u + ko);
            bl[nf] = *(const short8*)(wl + bBase + nf * 20480u + ko);
        }
        #pragma unroll
        for (int mf = 0; mf < 2; mf++)
            #pragma unroll
            for (int nf = 0; nf < 5; nf++) {
                acc[mf][nf] = __builtin_amdgcn_mfma_f32_16x16x32_bf16(ah[mf], bh[nf], acc[mf][nf], 0, 0, 0);
                acc[mf][nf] = __builtin_amdgcn_mfma_f32_16x16x32_bf16(al[mf], bh[nf], acc[mf][nf], 0, 0, 0);
                acc[mf][nf] = __builtin_amdgcn_mfma_f32_16x16x32_bf16(ah[mf], bl[nf], acc[mf][nf], 0, 0, 0);
            }
    }

    // epilogue: bias + bf16x2 split + frag-major q/k stores
    #pragma unroll
    for (int nf = 0; nf < 5; nf++) {
        int o = wave * 80 + nf * 16 + l15;
        bool isQ = (o < HH);
        float bias = isQ ? bq[o] : bk[o - HH];
        int oo = isQ ? o : (o - HH);
        unsigned short* dh = isQ ? qh : kh;
        unsigned short* dl = isQ ? ql : kl;
        unsigned ob = (unsigned)(oo >> 5) * 512u + ((oo >> 3) & 3) * 128u + (oo & 7);
        #pragma unroll
        for (int mf = 0; mf < 2; mf++) {
            unsigned fa0 = (unsigned)(mg0 + mf) * 2560u + ob + (l4 * 4) * 8u;
            #pragma unroll
            for (int r = 0; r < 4; r++) {
                float val = acc[mf][nf][r] + bias;
                unsigned short vh, vl;
                split2(val, vh, vl);
                dh[fa0 + r * 8] = vh;
                dl[fa0 + r * 8] = vl;
            }
        }
    }
}

// ---------------- Kernel 1b v2: v projection, v7 quadrant pipeline ----------------
__global__ __launch_bounds__(256, 3) void proj_v(
    const unsigned short* __restrict__ xh, const unsigned short* __restrict__ wv,
    const float* __restrict__ bv, unsigned short* __restrict__ vt)
{
    __shared__ __align__(16) unsigned short Sm[3 * 8192];   // 48 KiB

    const int bid = blockIdx.x;         // 0..1279
    const int xcd = bid & 7;
    const int q   = bid >> 3;           // 0..159
    const int mt  = xcd * 16 + q / 10;  // m-tile 0..127 (batch = xcd)
    const int ft  = q % 10;             // f-tile 0..9
    const int m0 = mt * 128;
    const int f0 = ft * 128;

    const int tid = threadIdx.x;
    const int wave = tid >> 6, lane = tid & 63;
    const int l15 = lane & 15, l4 = lane >> 4;
    const int wm = wave >> 1, wn = wave & 1;

    const unsigned short* AF = xh + (size_t)(m0 >> 4) * 20480;
    const unsigned short* BF = wv + (size_t)(f0 >> 4) * 20480;

    const int sp0 = tid, sp1 = 256 + tid;
    const unsigned sa0 = (unsigned)(sp0 >> 6) * 20480u + (sp0 & 63) * 8;
    const unsigned sa1 = (unsigned)(sp1 >> 6) * 20480u + (sp1 & 63) * 8;

    floatx4 acc[4][4] = {};

    auto STAGE = [&](int slot, int ks) {
        unsigned short* A  = Sm + slot * 8192;
        unsigned short* Bs = A + 4096;
        const unsigned ko = (unsigned)ks * 512u;
        gl16(AF + sa0 + ko, A  + sp0 * 8);
        gl16(BF + sa0 + ko, Bs + sp0 * 8);
        gl16(AF + sa1 + ko, A  + sp1 * 8);
        gl16(BF + sa1 + ko, Bs + sp1 * 8);
    };

    auto COMPUTE = [&](int slot) {
        const unsigned short* A  = Sm + slot * 8192;
        const unsigned short* Bs = A + 4096;
        short8 a[4], bb[4];
        #pragma unroll
        for (int mf = 0; mf < 4; mf++)
            a[mf] = *(const short8*)(A + ((wm * 4 + mf) * 64 + lane) * 8);
        #pragma unroll
        for (int nf = 0; nf < 4; nf++)
            bb[nf] = *(const short8*)(Bs + ((wn * 4 + nf) * 64 + lane) * 8);
        __builtin_amdgcn_s_setprio(1);
        #pragma unroll
        for (int mf = 0; mf < 4; mf++)
            #pragma unroll
            for (int nf = 0; nf < 4; nf++)
                acc[mf][nf] = __builtin_amdgcn_mfma_f32_16x16x32_bf16(a[mf], bb[nf], acc[mf][nf], 0, 0, 0);
        __builtin_amdgcn_s_setprio(0);
    };

    STAGE(0, 0); STAGE(1, 1); STAGE(2, 2);

    int s = 0;
    for (int kt = 0; kt < 37; ++kt) {              // 40 K-steps total
        asm volatile("s_waitcnt vmcnt(8)" ::: "memory");
        asm volatile("s_barrier" ::: "memory");
        COMPUTE(s);
        asm volatile("s_barrier" ::: "memory");
        STAGE(s, kt + 3);
        s = (s == 2) ? 0 : s + 1;
    }
    asm volatile("s_waitcnt vmcnt(8)" ::: "memory");
    asm volatile("s_barrier" ::: "memory");
    COMPUTE(s); s = (s == 2) ? 0 : s + 1;
    asm volatile("s_waitcnt vmcnt(4)" ::: "memory");
    asm volatile("s_barrier" ::: "memory");
    COMPUTE(s); s = (s == 2) ? 0 : s + 1;
    asm volatile("s_waitcnt vmcnt(0)" ::: "memory");
    asm volatile("s_barrier" ::: "memory");
    COMPUTE(s);

    // epilogue: bias + direct frag-major vt stores (ushort4 over r)
    const int b    = m0 >> 11;                    // == xcd
    const int tokb = (m0 & 2047) + wm * 64;
    unsigned short* vtB = vt + (size_t)b * LL * NN;
    float bvv[4];
    #pragma unroll
    for (int nf = 0; nf < 4; nf++)
        bvv[nf] = bv[f0 + wn * 64 + nf * 16 + l15];

    #pragma unroll
    for (int mf = 0; mf < 4; mf++)
        #pragma unroll
        for (int nf = 0; nf < 4; nf++) {
            int f   = f0 + wn * 64 + nf * 16 + l15;
            int tok = tokb + mf * 16 + l4 * 4;    // +r, r=0..3 contiguous in (tok&7)
            ushort4 u;
            u.x = f2bf(acc[mf][nf][0] + bvv[nf]);
            u.y = f2bf(acc[mf][nf][1] + bvv[nf]);
            u.z = f2bf(acc[mf][nf][2] + bvv[nf]);
            u.w = f2bf(acc[mf][nf][3] + bvv[nf]);
            *(ushort4*)(vtB + (size_t)(f >> 4) * 32768 + (tok >> 5) * 512
                        + ((tok >> 3) & 3) * 128 + (f & 15) * 8 + (tok & 7)) = u;
        }
}

// ---------------- Kernel 2a v2: S = exp(QK^T - SHIFT), 64-row blocks ----------------
__global__ __launch_bounds__(512, 2) void s_exp(
    const unsigned short* __restrict__ qhp, const unsigned short* __restrict__ qlp,
    const unsigned short* __restrict__ khp, const unsigned short* __restrict__ klp,
    unsigned short* __restrict__ P, float* __restrict__ Lsum)
{
    __shared__ float sums[8][64];
    const int bid = blockIdx.x;        // 0..255
    const int b   = bid & 7;           // one batch per XCD
    const int i0  = (bid >> 3) * 64;   // 64 q-rows
    const int tid = threadIdx.x;
    const int wave = tid >> 6, lane = tid & 63;
    const int l15 = lane & 15, l4 = lane >> 4;

    // resident A-frags: 4 rowtiles x 5 ks, hi+lo (160 VGPR)
    short8 aqh[4][5], aql[4][5];
    #pragma unroll
    for (int rt = 0; rt < 4; rt++) {
        const size_t rowb = (size_t)((b * NN + i0 + rt * 16) >> 4) * 2560 + lane * 8;
        #pragma unroll
        for (int ks = 0; ks < 5; ks++) {
            aqh[rt][ks] = *(const short8*)&qhp[rowb + ks * 512];
            aql[rt][ks] = *(const short8*)&qlp[rowb + ks * 512];
        }
    }

    float sr[4][4] = {};
    unsigned short* Pb = P + (size_t)b * NN * NN + (size_t)(i0 >> 4) * 32768;

    for (int c0 = 0; c0 < NN; c0 += 512) {
        const int jb = c0 + wave * 64;      // wave's 64-col stripe
        #pragma unroll
        for (int ct = 0; ct < 4; ct++) {
            const int tok0 = jb + ct * 16;                 // multiple of 16
            const int tok  = tok0 + l15;
            const size_t kbase = (size_t)((b * NN + tok0) >> 4) * 2560 + lane * 8;
            floatx4 a[4] = {{0,0,0,0},{0,0,0,0},{0,0,0,0},{0,0,0,0}};
            #pragma unroll
            for (int ks = 0; ks < 5; ks++) {
                short8 bh = *(const short8*)&khp[kbase + ks * 512];
                short8 bl = *(const short8*)&klp[kbase + ks * 512];
                #pragma unroll
                for (int rt = 0; rt < 4; rt++) {
                    a[rt] = __builtin_amdgcn_mfma_f32_16x16x32_bf16(aqh[rt][ks], bh, a[rt], 0, 0, 0);
                    a[rt] = __builtin_amdgcn_mfma_f32_16x16x32_bf16(aql[rt][ks], bh, a[rt], 0, 0, 0);
                    a[rt] = __builtin_amdgcn_mfma_f32_16x16x32_bf16(aqh[rt][ks], bl, a[rt], 0, 0, 0);
                }
            }
            const size_t tbase = (size_t)(tok >> 5) * 512 + ((tok >> 3) & 3) * 128 + (tok & 7);
            #pragma unroll
            for (int rt = 0; rt < 4; rt++)
                #pragma unroll
                for (int r = 0; r < 4; r++) {
                    float p = __expf(a[rt][r] - SHIFT);
                    Pb[tbase + (size_t)rt * 32768 + (l4 * 4 + r) * 8] = f2bf(p);
                    sr[rt][r] += p;
                }
        }
    }

    // reduce row sums over l15 (16 lanes), then across the 8 waves via LDS
    #pragma unroll
    for (int rt = 0; rt < 4; rt++)
        #pragma unroll
        for (int r = 0; r < 4; r++) {
            float v = sr[rt][r];
            v += __shfl_xor(v, 1);
            v += __shfl_xor(v, 2);
            v += __shfl_xor(v, 4);
            v += __shfl_xor(v, 8);
            if (l15 == 0) sums[wave][rt * 16 + l4 * 4 + r] = v;
        }
    __syncthreads();
    if (tid < 64) {
        float s = 0.f;
        #pragma unroll
        for (int w = 0; w < 8; w++) s += sums[w][tid];
        Lsum[(size_t)b * NN + i0 + tid] = s;
    }
}

// ---------------- Kernel 2b v7: frag-major quadrant GEMM (measured optimum) ----------------
// 128x128 tile, 4 waves 2x2 quadrants (64x64, acc 4x4), depth-3 rotating
// 48 KB LDS, counted vmcnt(8), setprio, frag-major linear gload_lds staging
// (0 conflicts), XCD batch swizzle. 99.5 us / MfmaUtil 38.5% — all measured
// single-axis deviations (8-wave/depth-2, 32x32 MFMA, 2-wave) were worse.
__global__ __launch_bounds__(256, 3) void pv_gemm(
    const unsigned short* __restrict__ P, const unsigned short* __restrict__ vt,
    const float* __restrict__ Lsum,
    const float* __restrict__ x, float* __restrict__ out)
{
    __shared__ __align__(16) unsigned short Sm[3 * 8192];   // 48 KiB

    const int p0 = blockIdx.x;          // 0..1279
    const int b  = p0 & 7;              // one batch per XCD
    const int t  = p0 >> 3;             // 0..159
    const int n0 = (t % 10) * 128;
    const int m0 = (t / 10) * 128;

    const int tid = threadIdx.x;
    const int wave = tid >> 6, lane = tid & 63;
    const int l15 = lane & 15, l4 = lane >> 4;
    const int wm = wave >> 1, wn = wave & 1;

    const unsigned short* PbF = P  + (size_t)b * NN * NN + (size_t)(m0 >> 4) * 32768;
    const unsigned short* VbF = vt + (size_t)b * LL * NN + (size_t)(n0 >> 4) * 32768;

    const int sp0 = tid, sp1 = 256 + tid;
    const unsigned sa0 = (unsigned)(sp0 >> 6) * 32768u + (sp0 & 63) * 8;
    const unsigned sa1 = (unsigned)(sp1 >> 6) * 32768u + (sp1 & 63) * 8;

    floatx4 acc[4][4] = {};

    auto STAGE = [&](int slot, int ks) {
        unsigned short* A  = Sm + slot * 8192;
        unsigned short* Bs = A + 4096;
        const unsigned ko = (unsigned)ks * 512u;
        gl16(PbF + sa0 + ko, A  + sp0 * 8);
        gl16(VbF + sa0 + ko, Bs + sp0 * 8);
        gl16(PbF + sa1 + ko, A  + sp1 * 8);
        gl16(VbF + sa1 + ko, Bs + sp1 * 8);
    };

    auto COMPUTE = [&](int slot) {
        const unsigned short* A  = Sm + slot * 8192;
        const unsigned short* Bs = A + 4096;
        short8 a[4], bb[4];
        #pragma unroll
        for (int mf = 0; mf < 4; mf++)
            a[mf] = *(const short8*)(A + ((wm * 4 + mf) * 64 + lane) * 8);
        #pragma unroll
        for (int nf = 0; nf < 4; nf++)
            bb[nf] = *(const short8*)(Bs + ((wn * 4 + nf) * 64 + lane) * 8);
        __builtin_amdgcn_s_setprio(1);
        #pragma unroll
        for (int mf = 0; mf < 4; mf++)
            #pragma unroll
            for (int nf = 0; nf < 4; nf++)
                acc[mf][nf] = __builtin_amdgcn_mfma_f32_16x16x32_bf16(a[mf], bb[nf], acc[mf][nf], 0, 0, 0);
        __builtin_amdgcn_s_setprio(0);
    };

    STAGE(0, 0); STAGE(1, 1); STAGE(2, 2);

    int s = 0;
    for (int kt = 0; kt < 61; ++kt) {
        asm volatile("s_waitcnt vmcnt(8)" ::: "memory");
        asm volatile("s_barrier" ::: "memory");
        COMPUTE(s);
        asm volatile("s_barrier" ::: "memory");
        STAGE(s, kt + 3);
        s = (s == 2) ? 0 : s + 1;
    }
    asm volatile("s_waitcnt vmcnt(8)" ::: "memory");
    asm volatile("s_barrier" ::: "memory");
    COMPUTE(s); s = (s == 2) ? 0 : s + 1;
    asm volatile("s_waitcnt vmcnt(4)" ::: "memory");
    asm volatile("s_barrier" ::: "memory");
    COMPUTE(s); s = (s == 2) ? 0 : s + 1;
    asm volatile("s_waitcnt vmcnt(0)" ::: "memory");
    asm volatile("s_barrier" ::: "memory");
    COMPUTE(s);

    float linv[4][4];
    #pragma unroll
    for (int mf = 0; mf < 4; mf++)
        #pragma unroll
        for (int r = 0; r < 4; r++)
            linv[mf][r] = 1.0f / Lsum[(size_t)b * NN + m0 + wm * 64 + mf * 16 + l4 * 4 + r];

    #pragma unroll
    for (int mf = 0; mf < 4; mf++)
        #pragma unroll
        for (int nf = 0; nf < 4; nf++)
            #pragma unroll
            for (int r = 0; r < 4; r++) {
                int row = m0 + wm * 64 + mf * 16 + l4 * 4 + r;
                int col = n0 + wn * 64 + nf * 16 + l15;
                size_t idx = ((size_t)b * NN + row) * LL + col;
                out[idx] = acc[mf][nf][r] * linv[mf][r] + x[idx];
            }
}

extern "C" void kernel_launch(void* const* d_in, const int* in_sizes, int n_in,
                              void* d_out, int out_size, void* d_ws, size_t ws_size,
                              hipStream_t stream) {
    const float* x  = (const float*)d_in[0];
    const float* Wq = (const float*)d_in[1];
    const float* bq = (const float*)d_in[2];
    const float* Wk = (const float*)d_in[3];
    const float* bk = (const float*)d_in[4];
    const float* Wv = (const float*)d_in[5];
    const float* bv = (const float*)d_in[6];
    float* out = (float*)d_out;

    // ws layout (~135 MB)
    unsigned short* wqk_h = (unsigned short*)d_ws;            // [20 o16][20480] frag-major
    unsigned short* wqk_l = wqk_h + (size_t)2*HH * LL;
    unsigned short* wv    = wqk_l + (size_t)2*HH * LL;        // [LL*LL] frag-major
    unsigned short* qh    = wv    + (size_t)LL * LL;          // [BN][HH] frag-major
    unsigned short* ql    = qh    + (size_t)BN * HH;
    unsigned short* kh    = ql    + (size_t)BN * HH;
    unsigned short* kl    = kh    + (size_t)BN * HH;
    unsigned short* vt    = kl    + (size_t)BN * HH;          // [BB][LL*NN] frag-major
    unsigned short* P     = vt    + (size_t)BB * LL * NN;     // [BB][NN*NN] frag-major
    float*          Lsum  = (float*)(P + (size_t)BB * NN * NN); // [BN]
    // Aliases (sequential-stream ordering makes these safe):
    //   xh (42 MB) aliases P (67 MB): consumed by proj_qk + proj_v, both
    //     complete before s_exp writes P.
    //   xl (42 MB) aliases vt (42 MB, exact fit): consumed only by proj_qk,
    //     which completes before proj_v writes vt.
    unsigned short* xh    = P;
    unsigned short* xl    = vt;

    cast_w<<<dim3(NO), dim3(256), 0, stream>>>(Wq, Wk, Wv, wqk_h, wqk_l, wv);

    cast_x<<<dim3(BN / 16), dim3(256), 0, stream>>>(x, xh, xl);

    // 512 blocks (2/CU), 4 waves: block = 32 rows x all 320 outputs
    proj_qk<<<dim3(BN / 32), dim3(256), 0, stream>>>(
        xh, xl, wqk_h, wqk_l, bq, bk, qh, ql, kh, kl);

    // flat 1280 blocks: xcd = bid&7 owns batch xcd; f-fastest within XCD
    proj_v<<<dim3(1280), dim3(256), 0, stream>>>(xh, wv, bv, vt);

    // flat 256 blocks of 512 threads: b = bid&7 (batch per XCD), 64 rows each
    s_exp<<<dim3(256), dim3(512), 0, stream>>>(qh, ql, kh, kl, P, Lsum);

    // flat 1280 blocks: b = bid&7 (batch per XCD), t = bid>>3 -> (n,m) tile
    pv_gemm<<<dim3(1280), dim3(256), 0, stream>>>(P, vt, Lsum, x, out);
}